// Round 12
// baseline (214.855 us; speedup 1.0000x reference)
//
#include <hip/hip_runtime.h>
#include <hip/hip_bf16.h>
#include <math.h>

// Problem constants: B=32, U=4096, K=4, N=2, K2=2, STRIDE=2048, UN=2048
// ws: (2, 4, 2048, 8192) f32 = 512 MB  -> the traffic floor
// GEMM per j: (32 x 8192) @ (8192 x 8192), f32 vector-FMA (no fp32 MFMA on CDNA4)
//
// r12: reg-streamed ws (no ws-LDS, no steady-state barriers), wave-private f-columns
// (no duplicate loads), depth-8 register ring, in-values via block-shared broadcast LDS.
//
// d_out layout (flat, return order):
//   x_out  [0,      131072)   (32,4096)
//   new_hs [131072, 393216)   (2,2,32,2048)
//   new_c  [393216, 917504)   (2,4,32,2048)
//
// d_ws layout:
//   in_t    at byte 0    : 2*8192*32 f32 = 2 MB        (in_t[j][k][b])
//   partial at byte 2 MB : 2*32*32*8192 bf16 = 33.5 MB (partial[j][s][b][f], bf16)

#define IN_T_ELEMS (2 * 8192 * 32)
#define NSPLIT 32

typedef unsigned short ushort_t;
typedef unsigned int uint_t;

__global__ __launch_bounds__(256) void transpose_in(const float* __restrict__ x,
                                                    const float* __restrict__ hs,
                                                    float* __restrict__ in_t) {
    int tid = blockIdx.x * 256 + threadIdx.x;   // [0, 524288)
    int b   = tid & 31;
    int kkd = (tid >> 5) & 8191;
    int j   = tid >> 18;
    float v;
    if (kkd < 4096) {
        v = x[b * 4096 + kkd];                        // x_chunks[b][kk][d] = x[b][kkd]
    } else {
        int kk = kkd >> 11;                           // 2 or 3
        int d  = kkd & 2047;
        v = hs[((j * 2 + (kk - 2)) * 32 + b) * 2048 + d];   // hs (2,2,32,2048)
    }
    in_t[tid] = v;
}

__device__ __forceinline__ ushort_t f2bf(float x) {
    __hip_bfloat16 h = __float2bfloat16(x);           // round-to-nearest
    return *reinterpret_cast<ushort_t*>(&h);
}

// 4 batches (a.x..a.w) x lane's 4 f-columns (wv)
__device__ __forceinline__ void fma_quad(float4* a4, float4 a, float4 wv) {
    a4[0].x = fmaf(a.x, wv.x, a4[0].x);
    a4[0].y = fmaf(a.x, wv.y, a4[0].y);
    a4[0].z = fmaf(a.x, wv.z, a4[0].z);
    a4[0].w = fmaf(a.x, wv.w, a4[0].w);
    a4[1].x = fmaf(a.y, wv.x, a4[1].x);
    a4[1].y = fmaf(a.y, wv.y, a4[1].y);
    a4[1].z = fmaf(a.y, wv.z, a4[1].z);
    a4[1].w = fmaf(a.y, wv.w, a4[1].w);
    a4[2].x = fmaf(a.z, wv.x, a4[2].x);
    a4[2].y = fmaf(a.z, wv.y, a4[2].y);
    a4[2].z = fmaf(a.z, wv.z, a4[2].z);
    a4[2].w = fmaf(a.z, wv.w, a4[2].w);
    a4[3].x = fmaf(a.w, wv.x, a4[3].x);
    a4[3].y = fmaf(a.w, wv.y, a4[3].y);
    a4[3].z = fmaf(a.w, wv.z, a4[3].z);
    a4[3].w = fmaf(a.w, wv.w, a4[3].w);
}

// Grid: 512 blocks = 2 (j) x 8 (f-tile of 1024) x 32 (K-chunk s of 256 rows) = exactly
// 2 blocks/CU (one clean pass). Block = 256 threads (4 waves). Wave w owns f-subtile
// [ft*1024 + w*256, +256) and ALL 32 batches -> waves load DISJOINT ws rows (no
// duplicate HBM requests), acc = 32 x float4 = 128 VGPR, launch_bounds(256,2).
// ws streams global->VGPR ring[8] (static idx, 8 KB/wave in flight ~ 2048 cyc of FMA
// cover vs ~900 cyc HBM latency). in-values: block-shared itile[256][32] (32 KB)
// staged once via global_load_lds, read as broadcast ds_read_b128 (8/row = ~12% of
// VALU). One barrier total; afterwards waves free-run.
__global__ __launch_bounds__(256, 2) void gemm_partial(const float* __restrict__ in_t,
                                                       const float* __restrict__ wsm,
                                                       ushort_t* __restrict__ partial) {
    __shared__ float itile[256][32];   // 32 KB

    int lin = blockIdx.x;              // [0, 512)
    int s   = lin & (NSPLIT - 1);
    int ft  = (lin >> 5) & 7;
    int j   = lin >> 8;
    int w    = __builtin_amdgcn_readfirstlane((int)(threadIdx.x >> 6));
    int lane = threadIdx.x & 63;
    int f0   = ft * 1024 + w * 256 + lane * 4;
    int k0   = s * 256;

    const float* __restrict__ wsrow = wsm + ((size_t)j * 8192 + k0) * 8192 + f0;

#define GLDS16(GP, LP)                                                          \
    __builtin_amdgcn_global_load_lds(                                           \
        (const __attribute__((address_space(1))) void*)(GP),                    \
        (__attribute__((address_space(3))) void*)(LP), 16, 0, 0)

    // ring prologue first (loads overlap the itile DMA + drain)
    float4 ring[8];
#pragma unroll
    for (int g = 0; g < 8; ++g)
        ring[g] = *(const float4*)(wsrow + (size_t)g * 8192);

    // stage itile: in_t[j][k0..k0+256][0..32] = 32 KB contiguous; chunk c = i*4+w (1 KB)
    const float* isrc = in_t + (size_t)(j * 8192 + k0) * 32;
#pragma unroll
    for (int i = 0; i < 8; ++i) {
        int c = i * 4 + w;
        GLDS16(isrc + c * 256 + lane * 4, &itile[0][0] + c * 256);
    }
    asm volatile("s_waitcnt vmcnt(0)" ::: "memory");
    __syncthreads();          // itile resident; ring also resident (harmless)
#undef GLDS16

    float4 acc[32];
#pragma unroll
    for (int b = 0; b < 32; ++b) acc[b] = make_float4(0.f, 0.f, 0.f, 0.f);

#pragma unroll 1
    for (int t = 0; t < 32; ++t) {
#pragma unroll
        for (int g = 0; g < 8; ++g) {
            int r = t * 8 + g;
            float4 wv = ring[g];
            int rn = (r + 8) & 255;                       // wrap: harmless L2-hot re-read
            ring[g] = *(const float4*)(wsrow + (size_t)rn * 8192);
            float4 av[8];
#pragma unroll
            for (int q = 0; q < 8; ++q)
                av[q] = *(const float4*)&itile[r][q * 4];  // broadcast reads
#pragma unroll
            for (int q = 0; q < 8; ++q)
                fma_quad(&acc[q * 4], av[q], wv);
        }
    }

    // partial[j][s][b][f] bf16: lane's 4 f -> uint2 (8 B), coalesced within wave
    size_t pbase = ((size_t)(j * NSPLIT + s) * 32) * 8192 + f0;
#pragma unroll
    for (int b = 0; b < 32; ++b) {
        uint_t p0 = (uint_t)f2bf(acc[b].x) | ((uint_t)f2bf(acc[b].y) << 16);
        uint_t p1 = (uint_t)f2bf(acc[b].z) | ((uint_t)f2bf(acc[b].w) << 16);
        uint2 v; v.x = p0; v.y = p1;
        *(uint2*)(partial + pbase + (size_t)b * 8192) = v;
    }
}

__device__ __forceinline__ float sigmoidf_(float v) { return 1.f / (1.f + expf(-v)); }
__device__ __forceinline__ float bf2f(ushort_t u) {
    uint_t x = ((uint_t)u) << 16;
    return *reinterpret_cast<float*>(&x);
}

// 131072 threads: tid -> (j, b, un)
__global__ __launch_bounds__(256) void epilogue(const ushort_t* __restrict__ partial,
                                                const float* __restrict__ cs,
                                                float* __restrict__ out) {
    int tid = blockIdx.x * 256 + threadIdx.x;
    int un  = tid & 2047;
    int b   = (tid >> 11) & 31;
    int j   = tid >> 16;

    float g4[4];
#pragma unroll
    for (int gate = 0; gate < 4; ++gate) {
        int f = gate * 2048 + un;
        float sum = 0.f;
#pragma unroll
        for (int s = 0; s < NSPLIT; ++s)
            sum += bf2f(partial[((size_t)((j * NSPLIT + s) * 32 + b)) * 8192 + f]);
        g4[gate] = sum;
    }
    float iv = sigmoidf_(g4[0]);
    float fv = sigmoidf_(g4[1]);
    float gv = tanhf(g4[2]);
    float ov = sigmoidf_(g4[3]);
    float ig = iv * gv;

#pragma unroll
    for (int kk = 0; kk < 4; ++kk) {
        float c_old = cs[((j * 4 + kk) * 32 + b) * 2048 + un];
        float c_new = fv * c_old + ig;
        float h     = ov * tanhf(c_new);
        out[393216 + ((j * 4 + kk) * 32 + b) * 2048 + un] = c_new;   // new_c
        if (kk == 0) {
            out[b * 4096 + j * 2048 + un] = h;                       // x_out
        }
        if (kk == j + 2) {
            // new_hs[jj][j][b][un] = h for jj in {0,1}
            out[131072 + ((0 * 2 + j) * 32 + b) * 2048 + un] = h;
            out[131072 + ((1 * 2 + j) * 32 + b) * 2048 + un] = h;
        }
    }
}

extern "C" void kernel_launch(void* const* d_in, const int* in_sizes, int n_in,
                              void* d_out, int out_size, void* d_ws, size_t ws_size,
                              hipStream_t stream) {
    const float* x   = (const float*)d_in[0];
    const float* hs  = (const float*)d_in[1];
    const float* cs  = (const float*)d_in[2];
    const float* wsm = (const float*)d_in[3];
    float* out = (float*)d_out;

    float* in_t       = (float*)d_ws;                                      // 2 MB
    ushort_t* partial = (ushort_t*)((char*)d_ws + (size_t)IN_T_ELEMS * 4); // 33.5 MB bf16

    transpose_in<<<524288 / 256, 256, 0, stream>>>(x, hs, in_t);
    gemm_partial<<<512, 256, 0, stream>>>(in_t, wsm, partial);
    epilogue<<<131072 / 256, 256, 0, stream>>>(partial, cs, out);
}